// Round 11
// baseline (187.606 us; speedup 1.0000x reference)
//
#include <hip/hip_runtime.h>
#include <math.h>

#define NP 16384
#define NR 8192
#define GRID 13
#define NCELL (GRID * GRID * GRID)
#define CAP 28
#define XST 396   // LDS row stride in shorts. 396*2B=792B=198 dwords; 198%32=6 ->
                  // ds_read_b128 bank = (6*l15+4*q)%32 spreads 64 lanes ~2-way (free),
                  // vs 392 (196%32=4 -> 8 banks, 8-way conflict, 2.9x cost).

typedef __attribute__((ext_vector_type(8))) short short8;
typedef __attribute__((ext_vector_type(4))) float f32x4;

__device__ inline unsigned short f2b(float f) {
  unsigned int x = __float_as_uint(f);
  return (unsigned short)((x + 0x7FFFu + ((x >> 16) & 1u)) >> 16);  // RNE
}
__device__ inline float blo(unsigned int u) { return __uint_as_float(u << 16); }
__device__ inline float bhi(unsigned int u) { return __uint_as_float(u & 0xffff0000u); }

// ---------------- fused preprocessing + cellCnt zeroing (R5-verified, unchanged)
__global__ __launch_bounds__(256) void k_pre(const float* __restrict__ rf,
                                             const float* __restrict__ rxyz,
                                             const float* __restrict__ pf,
                                             const float* __restrict__ s0, const float* __restrict__ s1,
                                             const float* __restrict__ s2, const float* __restrict__ s3,
                                             const float* __restrict__ s4, const float* __restrict__ s5,
                                             const float* __restrict__ s6, const float* __restrict__ s7,
                                             unsigned short* __restrict__ rgbTb,
                                             float4* __restrict__ rxyz4,
                                             unsigned short* __restrict__ fullp,
                                             unsigned short* __restrict__ dst,
                                             int* __restrict__ cellCnt) {
  __shared__ float tile[128][65];
  int b = blockIdx.x, t = threadIdx.x;
  if (b < 128) {
    int r0 = b * 64;
    for (int e = 0; e < 32; ++e) {
      int idx = t + e * 256;
      int c = idx >> 6, rl = idx & 63;
      tile[c][rl] = rf[c * NR + r0 + rl];
    }
    __syncthreads();
    for (int e = 0; e < 32; ++e) {
      int idx = t + e * 256;
      int rl = idx >> 7, c = idx & 127;
      rgbTb[(size_t)(r0 + rl) * 128 + c] = f2b(tile[c][rl]);
    }
    if (b == 0 && t < 128) rgbTb[(size_t)NR * 128 + t] = 0;
    if ((t >> 6) == 0) {
      int i = r0 + (t & 63);
      float x = rxyz[i * 3], y = rxyz[i * 3 + 1], z = rxyz[i * 3 + 2];
      rxyz4[i] = make_float4(x, y, z, 0.f);
    }
  } else if (b < 384) {
    int n0 = (b - 128) * 64;
    for (int e = 0; e < 8; ++e) {
      int idx = t + e * 256;
      int c = idx >> 6, nl = idx & 63;
      tile[c][nl] = pf[c * NP + n0 + nl];
    }
    __syncthreads();
    for (int e = 0; e < 8; ++e) {
      int idx = t + e * 256;
      int nl = idx >> 5, c = idx & 31;
      fullp[(size_t)(n0 + nl) * 32 + c] = f2b(tile[c][nl]);
    }
  } else if (b < 960) {
    const int groups[8] = {18432, 6144, 8192, 4096, 3200, 3200, 2560, 2048}; // short8 groups
    const int Cs[8]     = {384, 384, 256, 256, 160, 160, 160, 128};
    const int offs[8]   = {0, 147456, 196608, 262144, 294912, 320512, 346112, 366592};
    const float* srcs[8] = {s0, s1, s2, s3, s4, s5, s6, s7};
    int j = b - 384;
    int m = j / 72, bx = j % 72;
    int gidx = bx * 256 + t;
    if (gidx >= groups[m]) return;
    int C = Cs[m], NC = C >> 5;
    int ot = gidx / (NC * 64);
    int rem = gidx - ot * (NC * 64);
    int k = rem >> 6, lane = rem & 63;
    int q = lane >> 4, l15 = lane & 15;
    const float* sp = srcs[m] + (size_t)(ot * 16 + l15) * C + k * 32 + q * 8;
    float4 a = *(const float4*)sp, c4 = *(const float4*)(sp + 4);
    uint4 o;
    o.x = f2b(a.x) | ((unsigned int)f2b(a.y) << 16);
    o.y = f2b(a.z) | ((unsigned int)f2b(a.w) << 16);
    o.z = f2b(c4.x) | ((unsigned int)f2b(c4.y) << 16);
    o.w = f2b(c4.z) | ((unsigned int)f2b(c4.w) << 16);
    *(uint4*)(dst + offs[m] + (size_t)gidx * 8) = o;
  } else {
    int idx = (b - 960) * 256 + t;
    if (idx < NCELL) cellCnt[idx] = 0;
  }
}

// ---------------- build uniform grid over rgb points (cell = 1/13 > radius 0.075)
__global__ __launch_bounds__(64) void k_build(const float4* __restrict__ rxyz4,
                                              int* __restrict__ cellCnt,
                                              float4* __restrict__ cellTab) {
  int i = blockIdx.x * 64 + threadIdx.x;   // 8192
  float4 r = rxyz4[i];
  int cx = (int)(r.x * 13.f); cx = cx < 0 ? 0 : (cx > 12 ? 12 : cx);
  int cy = (int)(r.y * 13.f); cy = cy < 0 ? 0 : (cy > 12 ? 12 : cy);
  int cz = (int)(r.z * 13.f); cz = cz < 0 ? 0 : (cz > 12 ? 12 : cz);
  int cell = (cz * 13 + cy) * 13 + cx;
  int slot = atomicAdd(&cellCnt[cell], 1);
  if (slot < CAP) cellTab[(size_t)cell * CAP + slot] = make_float4(r.x, r.y, r.z, __int_as_float(i));
}

// ---------------- fused-MLP layer (R5 32-row shape, stride-396 LDS rows)
template <int C, int O, int COFF, bool BN, bool RELU>
__device__ __forceinline__ void mlp_layer(const unsigned short* __restrict__ W,
                                          const float* __restrict__ bias,
                                          const float* __restrict__ bnp,
                                          const unsigned short* Xs,
                                          unsigned short* Ys,
                                          int wo, int q, int l15, int lane) {
  constexpr int NC = C / 32;
  constexpr int NT = O / 16;
  constexpr int MT = (NT + 7) / 8;
  f32x4 acc[MT][2];
  short8 afb[2][MT];
  const unsigned short* wp[MT];
#pragma unroll
  for (int i = 0; i < MT; ++i) {
    acc[i][0] = (f32x4){0.f, 0.f, 0.f, 0.f};
    acc[i][1] = (f32x4){0.f, 0.f, 0.f, 0.f};
    int ot = wo + i * 8;
    wp[i] = W + ((size_t)(((ot < NT) ? ot : 0) * NC) * 64 + lane) * 8;
  }
#pragma unroll
  for (int k = 0; k < 2 && k < NC; ++k)
#pragma unroll
    for (int i = 0; i < MT; ++i)
      if (wo + i * 8 < NT) afb[k][i] = *(const short8*)(wp[i] + (size_t)k * 512);
  short8 bf0 = *(const short8*)&Xs[l15 * XST + q * 8];
  short8 bf1 = *(const short8*)&Xs[(16 + l15) * XST + q * 8];
#pragma unroll
  for (int k = 0; k < NC; ++k) {
    short8 nbf0 = bf0, nbf1 = bf1;
    if (k + 1 < NC) {                  // compile-time
      nbf0 = *(const short8*)&Xs[l15 * XST + (k + 1) * 32 + q * 8];
      nbf1 = *(const short8*)&Xs[(16 + l15) * XST + (k + 1) * 32 + q * 8];
    }
    int slot = k & 1;
#pragma unroll
    for (int i = 0; i < MT; ++i) {
      if (wo + i * 8 < NT) {           // folds for all layers but dh1/dh2 i=1
        acc[i][0] = __builtin_amdgcn_mfma_f32_16x16x32_bf16(afb[slot][i], bf0, acc[i][0], 0, 0, 0);
        acc[i][1] = __builtin_amdgcn_mfma_f32_16x16x32_bf16(afb[slot][i], bf1, acc[i][1], 0, 0, 0);
      }
    }
    if (k + 2 < NC) {                  // compile-time
#pragma unroll
      for (int i = 0; i < MT; ++i)
        if (wo + i * 8 < NT) afb[slot][i] = *(const short8*)(wp[i] + (size_t)(k + 2) * 512);
    }
    bf0 = nbf0; bf1 = nbf1;
  }
#pragma unroll
  for (int i = 0; i < MT; ++i) {
    int ot = wo + i * 8;
    if (ot >= NT) continue;
    int o4 = ot * 16 + q * 4;
    f32x4 bb = *(const f32x4*)(bias + o4);
    f32x4 sc, sh;
    if (BN) {
      f32x4 g  = *(const f32x4*)(bnp + o4);
      f32x4 be = *(const f32x4*)(bnp + O + o4);
      f32x4 mm = *(const f32x4*)(bnp + 2 * O + o4);
      f32x4 vv = *(const f32x4*)(bnp + 3 * O + o4);
#pragma unroll
      for (int r = 0; r < 4; ++r) {
        float inv = g[r] * rsqrtf(vv[r] + 1e-5f);
        sc[r] = inv; sh[r] = (bb[r] - mm[r]) * inv + be[r];
      }
    } else {
      sc = (f32x4){1.f, 1.f, 1.f, 1.f}; sh = bb;
    }
#pragma unroll
    for (int rt = 0; rt < 2; ++rt) {
      ushort4 u;
#pragma unroll
      for (int r = 0; r < 4; ++r) {
        float x = acc[i][rt][r] * sc[r] + sh[r];
        if (RELU) x = fmaxf(x, 0.f);
        ((unsigned short*)&u)[r] = f2b(x);
      }
      *(ushort4*)&Ys[(rt * 16 + l15) * XST + COFF + ot * 16 + q * 4] = u;
    }
  }
}

// ---------------- one-kernel MLP (R5-verified structure: 512 blocks x 32 rows,
// fused 3-NN prologue, 16 lanes/query) with stride-396 LDS rows.
__global__ __launch_bounds__(512) void k_mlp(
    const unsigned short* __restrict__ rgbTb,
    const float* __restrict__ pxyz,
    const int* __restrict__ cellCnt,
    const float4* __restrict__ cellTab,
    const unsigned short* __restrict__ fullp,
    const unsigned short* __restrict__ wcc1, const unsigned short* __restrict__ wcc2,
    const unsigned short* __restrict__ wco1, const unsigned short* __restrict__ wco2,
    const unsigned short* __restrict__ wdh1, const unsigned short* __restrict__ wdh2,
    const unsigned short* __restrict__ wdh3, const unsigned short* __restrict__ wsh1,
    const float* __restrict__ cc1_b, const float* __restrict__ cc_bn,
    const float* __restrict__ cc2_b,
    const float* __restrict__ co1_b, const float* __restrict__ co_bn,
    const float* __restrict__ co2_b,
    const float* __restrict__ dh1_b, const float* __restrict__ dh1_bn,
    const float* __restrict__ dh2_b, const float* __restrict__ dh2_bn,
    const float* __restrict__ dh3_b,
    const float* __restrict__ sh1_b, const float* __restrict__ sh_bn,
    const float* __restrict__ sh2_w, const float* __restrict__ sh2_b,
    float* __restrict__ out) {
  __shared__ unsigned short Ab[32 * XST];   // 24.75 KB
  __shared__ unsigned short Bb[32 * XST];   // 24.75 KB
  __shared__ int nbrS[32][3];
  int t = threadIdx.x, lane = t & 63, w = t >> 6;
  int wo = w & 7;                           // range [0,8) for guard folding
  int q = lane >> 4, l15 = lane & 15;
  int n0 = blockIdx.x * 32;
  // ---- fused 3-NN for this block's 32 queries (16 lanes/query, R5-verified)
  {
    int n = n0 + w * 4 + q;
    float px = pxyz[n * 3], py = pxyz[n * 3 + 1], pz = pxyz[n * 3 + 2];
    int cx = (int)(px * 13.f); cx = cx < 0 ? 0 : (cx > 12 ? 12 : cx);
    int cy = (int)(py * 13.f); cy = cy < 0 ? 0 : (cy > 12 ? 12 : cy);
    int cz = (int)(pz * 13.f); cz = cz < 0 ? 0 : (cz > 12 ? 12 : cz);
    const float R2L = 0.005626125f;
    const unsigned long long SENT = ((unsigned long long)__float_as_uint(R2L) << 32);
    unsigned long long k0 = SENT, k1 = SENT, k2 = SENT;
    for (int ci = l15; ci < 27; ci += 16) {
      int dz = ci / 9 - 1, dyc = (ci / 3) % 3 - 1, dxc = ci % 3 - 1;
      int zz = cz + dz, yy = cy + dyc, xx = cx + dxc;
      if ((unsigned)zz <= 12u && (unsigned)yy <= 12u && (unsigned)xx <= 12u) {
        int c = (zz * 13 + yy) * 13 + xx;
        int m = cellCnt[c]; m = m < CAP ? m : CAP;
        const float4* tp = cellTab + (size_t)c * CAP;
        for (int k = 0; k < m; ++k) {
          float4 qq = tp[k];
          float dxx = qq.x - px, dyy = qq.y - py, dzz = qq.z - pz;
          float d2 = fmaf(dxx, dxx, fmaf(dyy, dyy, dzz * dzz));
          unsigned long long key =
              ((unsigned long long)__float_as_uint(d2) << 32) | (unsigned int)__float_as_int(qq.w);
          if (key < k2) {
            if (key < k1) {
              k2 = k1;
              if (key < k0) { k1 = k0; k0 = key; }
              else          { k1 = key; }
            } else k2 = key;
          }
        }
      }
    }
    int pos = 0;
    unsigned long long res[3];
#pragma unroll
    for (int r = 0; r < 3; ++r) {
      unsigned long long cur = (pos == 0) ? k0 : (pos == 1) ? k1 : (pos == 2) ? k2 : ~0ull;
      unsigned long long m = cur;
#pragma unroll
      for (int o = 1; o <= 8; o <<= 1) {
        unsigned long long other = __shfl_xor(m, o);
        m = other < m ? other : m;
      }
      res[r] = m;
      if (cur == m) ++pos;
    }
    if (l15 == 0) {
      const float R2 = 0.075f * 0.075f;
      float d0 = __uint_as_float((unsigned int)(res[0] >> 32));
      float d1 = __uint_as_float((unsigned int)(res[1] >> 32));
      float d2v = __uint_as_float((unsigned int)(res[2] >> 32));
      nbrS[w * 4 + q][0] = (d0 > R2) ? NR : (int)(res[0] & 0xffffffffu);
      nbrS[w * 4 + q][1] = (d1 > R2) ? NR : (int)(res[1] & 0xffffffffu);
      nbrS[w * 4 + q][2] = (d2v > R2) ? NR : (int)(res[2] & 0xffffffffu);
    }
  }
  __syncthreads();
  unsigned int mreg[4];                     // maxf held in registers
  // ---- gather 3 neighbor rows + maxf (indices clamped: poison-proof under replay)
#pragma unroll
  for (int pj = 0; pj < 4; ++pj) {
    int r = w * 4 + pj;
    unsigned int j0 = (unsigned int)nbrS[r][0]; j0 = j0 > NR ? NR : j0;
    unsigned int j1 = (unsigned int)nbrS[r][1]; j1 = j1 > NR ? NR : j1;
    unsigned int j2 = (unsigned int)nbrS[r][2]; j2 = j2 > NR ? NR : j2;
    unsigned int a = ((const unsigned int*)(rgbTb + (size_t)j0 * 128))[lane];
    unsigned int b = ((const unsigned int*)(rgbTb + (size_t)j1 * 128))[lane];
    unsigned int c = ((const unsigned int*)(rgbTb + (size_t)j2 * 128))[lane];
    unsigned int* xr = (unsigned int*)&Ab[r * XST];
    xr[lane] = a; xr[64 + lane] = b; xr[128 + lane] = c;
    float ml = fmaxf(blo(a), fmaxf(blo(b), blo(c)));
    float mh = fmaxf(bhi(a), fmaxf(bhi(b), bhi(c)));
    mreg[pj] = (__float_as_uint(mh) & 0xffff0000u) | (__float_as_uint(ml) >> 16);
  }
  __syncthreads();
  mlp_layer<384, 384, 0, true,  true >(wcc1, cc1_b, cc_bn, Ab, Bb, wo, q, l15, lane);
  __syncthreads();
  // cc2 writes Ab cols 0..127; maxf (registers) -> Ab cols 128..255 — disjoint.
#pragma unroll
  for (int pj = 0; pj < 4; ++pj)
    ((unsigned int*)&Ab[(w * 4 + pj) * XST])[64 + lane] = mreg[pj];
  mlp_layer<384, 128, 0, false, false>(wcc2, cc2_b, nullptr, Bb, Ab, wo, q, l15, lane);
  __syncthreads();
  mlp_layer<256, 256, 0, true,  true >(wco1, co1_b, co_bn, Ab, Bb, wo, q, l15, lane);
  __syncthreads();
  mlp_layer<256, 128, 32, false, false>(wco2, co2_b, nullptr, Bb, Ab, wo, q, l15, lane);
  for (int idx = t; idx < 128; idx += 512) {    // pcd feats -> Ab cols 0..31
    int row = idx >> 2, c8 = idx & 3;
    *(uint4*)&Ab[row * XST + c8 * 8] = *(const uint4*)(fullp + (size_t)(n0 + row) * 32 + c8 * 8);
  }
  __syncthreads();
  mlp_layer<160, 160, 0, true,  true >(wdh1, dh1_b, dh1_bn, Ab, Bb, wo, q, l15, lane);
  __syncthreads();
  mlp_layer<160, 160, 0, true,  true >(wdh2, dh2_b, dh2_bn, Bb, Ab, wo, q, l15, lane);
  __syncthreads();
  mlp_layer<160, 128, 0, false, false>(wdh3, dh3_b, nullptr, Ab, Bb, wo, q, l15, lane); // fp -> Bb
  __syncthreads();
  mlp_layer<128, 128, 0, true,  true >(wsh1, sh1_b, sh_bn, Bb, Ab, wo, q, l15, lane);   // s  -> Ab
  __syncthreads();
  // ---- tail: wave w handles rows w*4 .. w*4+3 (score from Ab, norm from Bb)
  int col8 = (lane & 15) * 8;
  float4 w0 = *(const float4*)(sh2_w + col8);
  float4 wA = *(const float4*)(sh2_w + col8 + 4);
  float bvv = sh2_b[0];
  int row = w * 4 + (lane >> 4);
  uint4 raw = *(const uint4*)&Ab[row * XST + col8];
  float acc = blo(raw.x) * w0.x + bhi(raw.x) * w0.y + blo(raw.y) * w0.z + bhi(raw.y) * w0.w +
              blo(raw.z) * wA.x + bhi(raw.z) * wA.y + blo(raw.w) * wA.z + bhi(raw.w) * wA.w;
  acc += __shfl_xor(acc, 1); acc += __shfl_xor(acc, 2);
  acc += __shfl_xor(acc, 4); acc += __shfl_xor(acc, 8);
  if ((lane & 15) == 0) out[49152 + n0 + row] = 1.f / (1.f + expf(-(acc + bvv)));
  uint4 rf = *(const uint4*)&Bb[row * XST + col8];
  float v[8] = {blo(rf.x), bhi(rf.x), blo(rf.y), bhi(rf.y),
                blo(rf.z), bhi(rf.z), blo(rf.w), bhi(rf.w)};
  float s = 0.f;
#pragma unroll
  for (int i = 0; i < 8; ++i) s = fmaf(v[i], v[i], s);
  s += __shfl_xor(s, 1); s += __shfl_xor(s, 2);
  s += __shfl_xor(s, 4); s += __shfl_xor(s, 8);
  float inv = 1.f / fmaxf(sqrtf(s), 1e-12f);
  float* op = out + 65536 + (size_t)(n0 + row) * 128 + col8;
  *(float4*)op = make_float4(v[0] * inv, v[1] * inv, v[2] * inv, v[3] * inv);
  *(float4*)(op + 4) = make_float4(v[4] * inv, v[5] * inv, v[6] * inv, v[7] * inv);
  for (int i = t; i < 96; i += 512) out[n0 * 3 + i] = pxyz[n0 * 3 + i];
}

extern "C" void kernel_launch(void* const* d_in, const int* in_sizes, int n_in,
                              void* d_out, int out_size, void* d_ws, size_t ws_size,
                              hipStream_t stream) {
  const float* pcd_xyz = (const float*)d_in[0];
  const float* rgb_xyz = (const float*)d_in[1];
  const float* pcd_f   = (const float*)d_in[2];
  const float* rgb_f   = (const float*)d_in[3];
  const float* cc1_w = (const float*)d_in[4];  const float* cc1_b = (const float*)d_in[5];
  const float* cc_bn = (const float*)d_in[6];
  const float* cc2_w = (const float*)d_in[7];  const float* cc2_b = (const float*)d_in[8];
  const float* co1_w = (const float*)d_in[9];  const float* co1_b = (const float*)d_in[10];
  const float* co_bn = (const float*)d_in[11];
  const float* co2_w = (const float*)d_in[12]; const float* co2_b = (const float*)d_in[13];
  const float* dh1_w = (const float*)d_in[14]; const float* dh1_b = (const float*)d_in[15];
  const float* dh1_bn = (const float*)d_in[16];
  const float* dh2_w = (const float*)d_in[17]; const float* dh2_b = (const float*)d_in[18];
  const float* dh2_bn = (const float*)d_in[19];
  const float* dh3_w = (const float*)d_in[20]; const float* dh3_b = (const float*)d_in[21];
  const float* sh1_w = (const float*)d_in[22]; const float* sh1_b = (const float*)d_in[23];
  const float* sh_bn = (const float*)d_in[24];
  const float* sh2_w = (const float*)d_in[25]; const float* sh2_b = (const float*)d_in[26];

  char* ws = (char*)d_ws;
  float* out = (float*)d_out;

  unsigned short* wb    = (unsigned short*)(ws);              // 766 KB
  unsigned short* rgbTb = (unsigned short*)(ws + 0x100000);   // 2.1 MB
  float4* rxyz4         = (float4*)(ws + 0x320000);           // 128 KB
  int*    cellCnt       = (int*)(ws + 0x480000);              // 8.8 KB
  float4* cellTab       = (float4*)(ws + 0x490000);           // 984 KB
  unsigned short* fullp = (unsigned short*)(ws + 0xA00000);   // (NP,32) bf16 = 1 MB

  unsigned short* wb_cc1 = wb;
  unsigned short* wb_cc2 = wb + 147456;
  unsigned short* wb_co1 = wb + 196608;
  unsigned short* wb_co2 = wb + 262144;
  unsigned short* wb_dh1 = wb + 294912;
  unsigned short* wb_dh2 = wb + 320512;
  unsigned short* wb_dh3 = wb + 346112;
  unsigned short* wb_sh1 = wb + 366592;

  k_pre<<<969, 256, 0, stream>>>(rgb_f, rgb_xyz, pcd_f,
                                 cc1_w, cc2_w, co1_w, co2_w, dh1_w, dh2_w, dh3_w, sh1_w,
                                 rgbTb, rxyz4, fullp, wb, cellCnt);
  k_build<<<128, 64, 0, stream>>>(rxyz4, cellCnt, cellTab);
  k_mlp<<<512, 512, 0, stream>>>(rgbTb, pcd_xyz, cellCnt, cellTab, fullp,
                                 wb_cc1, wb_cc2, wb_co1, wb_co2,
                                 wb_dh1, wb_dh2, wb_dh3, wb_sh1,
                                 cc1_b, cc_bn, cc2_b, co1_b, co_bn, co2_b,
                                 dh1_b, dh1_bn, dh2_b, dh2_bn, dh3_b,
                                 sh1_b, sh_bn, sh2_w, sh2_b,
                                 out);
}

// Round 12
// 151.576 us; speedup vs baseline: 1.2377x; 1.2377x over previous
//
#include <hip/hip_runtime.h>
#include <math.h>

#define NP 16384
#define NR 8192
#define GRID 13
#define NCELL (GRID * GRID * GRID)
#define CAP 28

typedef __attribute__((ext_vector_type(8))) short short8;
typedef __attribute__((ext_vector_type(4))) float f32x4;

__device__ inline unsigned short f2b(float f) {
  unsigned int x = __float_as_uint(f);
  return (unsigned short)((x + 0x7FFFu + ((x >> 16) & 1u)) >> 16);  // RNE
}
__device__ inline float blo(unsigned int u) { return __uint_as_float(u << 16); }
__device__ inline float bhi(unsigned int u) { return __uint_as_float(u & 0xffff0000u); }

// ---------------- fused preprocessing + cellCnt zeroing (R5-verified, 154.3 µs config)
__global__ __launch_bounds__(256) void k_pre(const float* __restrict__ rf,
                                             const float* __restrict__ rxyz,
                                             const float* __restrict__ pf,
                                             const float* __restrict__ s0, const float* __restrict__ s1,
                                             const float* __restrict__ s2, const float* __restrict__ s3,
                                             const float* __restrict__ s4, const float* __restrict__ s5,
                                             const float* __restrict__ s6, const float* __restrict__ s7,
                                             unsigned short* __restrict__ rgbTb,
                                             float4* __restrict__ rxyz4,
                                             unsigned short* __restrict__ fullp,
                                             unsigned short* __restrict__ dst,
                                             int* __restrict__ cellCnt) {
  __shared__ float tile[128][65];
  int b = blockIdx.x, t = threadIdx.x;
  if (b < 128) {
    int r0 = b * 64;
    for (int e = 0; e < 32; ++e) {
      int idx = t + e * 256;
      int c = idx >> 6, rl = idx & 63;
      tile[c][rl] = rf[c * NR + r0 + rl];
    }
    __syncthreads();
    for (int e = 0; e < 32; ++e) {
      int idx = t + e * 256;
      int rl = idx >> 7, c = idx & 127;
      rgbTb[(size_t)(r0 + rl) * 128 + c] = f2b(tile[c][rl]);
    }
    if (b == 0 && t < 128) rgbTb[(size_t)NR * 128 + t] = 0;
    if ((t >> 6) == 0) {
      int i = r0 + (t & 63);
      float x = rxyz[i * 3], y = rxyz[i * 3 + 1], z = rxyz[i * 3 + 2];
      rxyz4[i] = make_float4(x, y, z, 0.f);
    }
  } else if (b < 384) {
    int n0 = (b - 128) * 64;
    for (int e = 0; e < 8; ++e) {
      int idx = t + e * 256;
      int c = idx >> 6, nl = idx & 63;
      tile[c][nl] = pf[c * NP + n0 + nl];
    }
    __syncthreads();
    for (int e = 0; e < 8; ++e) {
      int idx = t + e * 256;
      int nl = idx >> 5, c = idx & 31;
      fullp[(size_t)(n0 + nl) * 32 + c] = f2b(tile[c][nl]);
    }
  } else if (b < 960) {
    const int groups[8] = {18432, 6144, 8192, 4096, 3200, 3200, 2560, 2048}; // short8 groups
    const int Cs[8]     = {384, 384, 256, 256, 160, 160, 160, 128};
    const int offs[8]   = {0, 147456, 196608, 262144, 294912, 320512, 346112, 366592};
    const float* srcs[8] = {s0, s1, s2, s3, s4, s5, s6, s7};
    int j = b - 384;
    int m = j / 72, bx = j % 72;
    int gidx = bx * 256 + t;
    if (gidx >= groups[m]) return;
    int C = Cs[m], NC = C >> 5;
    int ot = gidx / (NC * 64);
    int rem = gidx - ot * (NC * 64);
    int k = rem >> 6, lane = rem & 63;
    int q = lane >> 4, l15 = lane & 15;
    const float* sp = srcs[m] + (size_t)(ot * 16 + l15) * C + k * 32 + q * 8;
    float4 a = *(const float4*)sp, c4 = *(const float4*)(sp + 4);
    uint4 o;
    o.x = f2b(a.x) | ((unsigned int)f2b(a.y) << 16);
    o.y = f2b(a.z) | ((unsigned int)f2b(a.w) << 16);
    o.z = f2b(c4.x) | ((unsigned int)f2b(c4.y) << 16);
    o.w = f2b(c4.z) | ((unsigned int)f2b(c4.w) << 16);
    *(uint4*)(dst + offs[m] + (size_t)gidx * 8) = o;
  } else {
    int idx = (b - 960) * 256 + t;
    if (idx < NCELL) cellCnt[idx] = 0;
  }
}

// ---------------- build uniform grid over rgb points (cell = 1/13 > radius 0.075)
__global__ __launch_bounds__(64) void k_build(const float4* __restrict__ rxyz4,
                                              int* __restrict__ cellCnt,
                                              float4* __restrict__ cellTab) {
  int i = blockIdx.x * 64 + threadIdx.x;   // 8192
  float4 r = rxyz4[i];
  int cx = (int)(r.x * 13.f); cx = cx < 0 ? 0 : (cx > 12 ? 12 : cx);
  int cy = (int)(r.y * 13.f); cy = cy < 0 ? 0 : (cy > 12 ? 12 : cy);
  int cz = (int)(r.z * 13.f); cz = cz < 0 ? 0 : (cz > 12 ? 12 : cz);
  int cell = (cz * 13 + cy) * 13 + cx;
  int slot = atomicAdd(&cellCnt[cell], 1);
  if (slot < CAP) cellTab[(size_t)cell * CAP + slot] = make_float4(r.x, r.y, r.z, __int_as_float(i));
}

// ---------------- fused-MLP layer (R5-verified, stride-392 LDS rows)
template <int C, int O, int COFF, bool BN, bool RELU>
__device__ __forceinline__ void mlp_layer(const unsigned short* __restrict__ W,
                                          const float* __restrict__ bias,
                                          const float* __restrict__ bnp,
                                          const unsigned short* Xs,
                                          unsigned short* Ys,
                                          int wo, int q, int l15, int lane) {
  constexpr int NC = C / 32;
  constexpr int NT = O / 16;
  constexpr int MT = (NT + 7) / 8;
  f32x4 acc[MT][2];
  short8 afb[2][MT];
  const unsigned short* wp[MT];
#pragma unroll
  for (int i = 0; i < MT; ++i) {
    acc[i][0] = (f32x4){0.f, 0.f, 0.f, 0.f};
    acc[i][1] = (f32x4){0.f, 0.f, 0.f, 0.f};
    int ot = wo + i * 8;
    wp[i] = W + ((size_t)(((ot < NT) ? ot : 0) * NC) * 64 + lane) * 8;
  }
#pragma unroll
  for (int k = 0; k < 2 && k < NC; ++k)
#pragma unroll
    for (int i = 0; i < MT; ++i)
      if (wo + i * 8 < NT) afb[k][i] = *(const short8*)(wp[i] + (size_t)k * 512);
  short8 bf0 = *(const short8*)&Xs[l15 * 392 + q * 8];
  short8 bf1 = *(const short8*)&Xs[(16 + l15) * 392 + q * 8];
#pragma unroll
  for (int k = 0; k < NC; ++k) {
    short8 nbf0 = bf0, nbf1 = bf1;
    if (k + 1 < NC) {                  // compile-time
      nbf0 = *(const short8*)&Xs[l15 * 392 + (k + 1) * 32 + q * 8];
      nbf1 = *(const short8*)&Xs[(16 + l15) * 392 + (k + 1) * 32 + q * 8];
    }
    int slot = k & 1;
#pragma unroll
    for (int i = 0; i < MT; ++i) {
      if (wo + i * 8 < NT) {           // folds for all layers but dh1/dh2 i=1
        acc[i][0] = __builtin_amdgcn_mfma_f32_16x16x32_bf16(afb[slot][i], bf0, acc[i][0], 0, 0, 0);
        acc[i][1] = __builtin_amdgcn_mfma_f32_16x16x32_bf16(afb[slot][i], bf1, acc[i][1], 0, 0, 0);
      }
    }
    if (k + 2 < NC) {                  // compile-time
#pragma unroll
      for (int i = 0; i < MT; ++i)
        if (wo + i * 8 < NT) afb[slot][i] = *(const short8*)(wp[i] + (size_t)(k + 2) * 512);
    }
    bf0 = nbf0; bf1 = nbf1;
  }
#pragma unroll
  for (int i = 0; i < MT; ++i) {
    int ot = wo + i * 8;
    if (ot >= NT) continue;
    int o4 = ot * 16 + q * 4;
    f32x4 bb = *(const f32x4*)(bias + o4);
    f32x4 sc, sh;
    if (BN) {
      f32x4 g  = *(const f32x4*)(bnp + o4);
      f32x4 be = *(const f32x4*)(bnp + O + o4);
      f32x4 mm = *(const f32x4*)(bnp + 2 * O + o4);
      f32x4 vv = *(const f32x4*)(bnp + 3 * O + o4);
#pragma unroll
      for (int r = 0; r < 4; ++r) {
        float inv = g[r] * rsqrtf(vv[r] + 1e-5f);
        sc[r] = inv; sh[r] = (bb[r] - mm[r]) * inv + be[r];
      }
    } else {
      sc = (f32x4){1.f, 1.f, 1.f, 1.f}; sh = bb;
    }
#pragma unroll
    for (int rt = 0; rt < 2; ++rt) {
      ushort4 u;
#pragma unroll
      for (int r = 0; r < 4; ++r) {
        float x = acc[i][rt][r] * sc[r] + sh[r];
        if (RELU) x = fmaxf(x, 0.f);
        ((unsigned short*)&u)[r] = f2b(x);
      }
      *(ushort4*)&Ys[(rt * 16 + l15) * 392 + COFF + ot * 16 + q * 4] = u;
    }
  }
}

// ---------------- one-kernel MLP with FUSED 3-NN prologue (R5-verified).
// 32 queries/block x 16 lanes each = 512 threads; lane l15 scans cells
// {l15, l15+16} of the 3x3x3 neighborhood (cell-disjoint). Per-lane sorted
// top-3 lexicographic (d2_bits<<32)|idx keys; 3-round pop-min merge over
// __shfl_xor {1,2,4,8} within the aligned 16-lane group.
__global__ __launch_bounds__(512) void k_mlp(
    const unsigned short* __restrict__ rgbTb,
    const float* __restrict__ pxyz,
    const int* __restrict__ cellCnt,
    const float4* __restrict__ cellTab,
    const unsigned short* __restrict__ fullp,
    const unsigned short* __restrict__ wcc1, const unsigned short* __restrict__ wcc2,
    const unsigned short* __restrict__ wco1, const unsigned short* __restrict__ wco2,
    const unsigned short* __restrict__ wdh1, const unsigned short* __restrict__ wdh2,
    const unsigned short* __restrict__ wdh3, const unsigned short* __restrict__ wsh1,
    const float* __restrict__ cc1_b, const float* __restrict__ cc_bn,
    const float* __restrict__ cc2_b,
    const float* __restrict__ co1_b, const float* __restrict__ co_bn,
    const float* __restrict__ co2_b,
    const float* __restrict__ dh1_b, const float* __restrict__ dh1_bn,
    const float* __restrict__ dh2_b, const float* __restrict__ dh2_bn,
    const float* __restrict__ dh3_b,
    const float* __restrict__ sh1_b, const float* __restrict__ sh_bn,
    const float* __restrict__ sh2_w, const float* __restrict__ sh2_b,
    float* __restrict__ out) {
  __shared__ unsigned short Ab[32 * 392];   // 24.5 KB
  __shared__ unsigned short Bb[32 * 392];   // 24.5 KB
  __shared__ int nbrS[32][3];
  int t = threadIdx.x, lane = t & 63, w = t >> 6;
  int wo = w & 7;                           // range [0,8) for guard folding
  int q = lane >> 4, l15 = lane & 15;
  int n0 = blockIdx.x * 32;
  // ---- fused 3-NN for this block's 32 queries
  {
    int n = n0 + w * 4 + q;
    float px = pxyz[n * 3], py = pxyz[n * 3 + 1], pz = pxyz[n * 3 + 2];
    int cx = (int)(px * 13.f); cx = cx < 0 ? 0 : (cx > 12 ? 12 : cx);
    int cy = (int)(py * 13.f); cy = cy < 0 ? 0 : (cy > 12 ? 12 : cy);
    int cz = (int)(pz * 13.f); cz = cz < 0 ? 0 : (cz > 12 ? 12 : cz);
    const float R2L = 0.005626125f;
    const unsigned long long SENT = ((unsigned long long)__float_as_uint(R2L) << 32);
    unsigned long long k0 = SENT, k1 = SENT, k2 = SENT;
    for (int ci = l15; ci < 27; ci += 16) {
      int dz = ci / 9 - 1, dyc = (ci / 3) % 3 - 1, dxc = ci % 3 - 1;
      int zz = cz + dz, yy = cy + dyc, xx = cx + dxc;
      if ((unsigned)zz <= 12u && (unsigned)yy <= 12u && (unsigned)xx <= 12u) {
        int c = (zz * 13 + yy) * 13 + xx;
        int m = cellCnt[c]; m = m < CAP ? m : CAP;
        const float4* tp = cellTab + (size_t)c * CAP;
        for (int k = 0; k < m; ++k) {
          float4 qq = tp[k];
          float dxx = qq.x - px, dyy = qq.y - py, dzz = qq.z - pz;
          float d2 = fmaf(dxx, dxx, fmaf(dyy, dyy, dzz * dzz));
          unsigned long long key =
              ((unsigned long long)__float_as_uint(d2) << 32) | (unsigned int)__float_as_int(qq.w);
          if (key < k2) {
            if (key < k1) {
              k2 = k1;
              if (key < k0) { k1 = k0; k0 = key; }
              else          { k1 = key; }
            } else k2 = key;
          }
        }
      }
    }
    int pos = 0;
    unsigned long long res[3];
#pragma unroll
    for (int r = 0; r < 3; ++r) {
      unsigned long long cur = (pos == 0) ? k0 : (pos == 1) ? k1 : (pos == 2) ? k2 : ~0ull;
      unsigned long long m = cur;
#pragma unroll
      for (int o = 1; o <= 8; o <<= 1) {
        unsigned long long other = __shfl_xor(m, o);
        m = other < m ? other : m;
      }
      res[r] = m;
      if (cur == m) ++pos;
    }
    if (l15 == 0) {
      const float R2 = 0.075f * 0.075f;
      float d0 = __uint_as_float((unsigned int)(res[0] >> 32));
      float d1 = __uint_as_float((unsigned int)(res[1] >> 32));
      float d2v = __uint_as_float((unsigned int)(res[2] >> 32));
      nbrS[w * 4 + q][0] = (d0 > R2) ? NR : (int)(res[0] & 0xffffffffu);
      nbrS[w * 4 + q][1] = (d1 > R2) ? NR : (int)(res[1] & 0xffffffffu);
      nbrS[w * 4 + q][2] = (d2v > R2) ? NR : (int)(res[2] & 0xffffffffu);
    }
  }
  __syncthreads();
  unsigned int mreg[4];                     // maxf held in registers
  // ---- gather 3 neighbor rows + maxf (indices clamped: poison-proof under replay)
#pragma unroll
  for (int pj = 0; pj < 4; ++pj) {
    int r = w * 4 + pj;
    unsigned int j0 = (unsigned int)nbrS[r][0]; j0 = j0 > NR ? NR : j0;
    unsigned int j1 = (unsigned int)nbrS[r][1]; j1 = j1 > NR ? NR : j1;
    unsigned int j2 = (unsigned int)nbrS[r][2]; j2 = j2 > NR ? NR : j2;
    unsigned int a = ((const unsigned int*)(rgbTb + (size_t)j0 * 128))[lane];
    unsigned int b = ((const unsigned int*)(rgbTb + (size_t)j1 * 128))[lane];
    unsigned int c = ((const unsigned int*)(rgbTb + (size_t)j2 * 128))[lane];
    unsigned int* xr = (unsigned int*)&Ab[r * 392];
    xr[lane] = a; xr[64 + lane] = b; xr[128 + lane] = c;
    float ml = fmaxf(blo(a), fmaxf(blo(b), blo(c)));
    float mh = fmaxf(bhi(a), fmaxf(bhi(b), bhi(c)));
    mreg[pj] = (__float_as_uint(mh) & 0xffff0000u) | (__float_as_uint(ml) >> 16);
  }
  __syncthreads();
  mlp_layer<384, 384, 0, true,  true >(wcc1, cc1_b, cc_bn, Ab, Bb, wo, q, l15, lane);
  __syncthreads();
  // cc2 writes Ab cols 0..127; maxf (registers) -> Ab cols 128..255 — disjoint.
#pragma unroll
  for (int pj = 0; pj < 4; ++pj)
    ((unsigned int*)&Ab[(w * 4 + pj) * 392])[64 + lane] = mreg[pj];
  mlp_layer<384, 128, 0, false, false>(wcc2, cc2_b, nullptr, Bb, Ab, wo, q, l15, lane);
  __syncthreads();
  mlp_layer<256, 256, 0, true,  true >(wco1, co1_b, co_bn, Ab, Bb, wo, q, l15, lane);
  __syncthreads();
  mlp_layer<256, 128, 32, false, false>(wco2, co2_b, nullptr, Bb, Ab, wo, q, l15, lane);
  for (int idx = t; idx < 128; idx += 512) {    // pcd feats -> Ab cols 0..31
    int row = idx >> 2, c8 = idx & 3;
    *(uint4*)&Ab[row * 392 + c8 * 8] = *(const uint4*)(fullp + (size_t)(n0 + row) * 32 + c8 * 8);
  }
  __syncthreads();
  mlp_layer<160, 160, 0, true,  true >(wdh1, dh1_b, dh1_bn, Ab, Bb, wo, q, l15, lane);
  __syncthreads();
  mlp_layer<160, 160, 0, true,  true >(wdh2, dh2_b, dh2_bn, Bb, Ab, wo, q, l15, lane);
  __syncthreads();
  mlp_layer<160, 128, 0, false, false>(wdh3, dh3_b, nullptr, Ab, Bb, wo, q, l15, lane); // fp -> Bb
  __syncthreads();
  mlp_layer<128, 128, 0, true,  true >(wsh1, sh1_b, sh_bn, Bb, Ab, wo, q, l15, lane);   // s  -> Ab
  __syncthreads();
  // ---- tail: wave w handles rows w*4 .. w*4+3 (score from Ab, norm from Bb)
  int col8 = (lane & 15) * 8;
  float4 w0 = *(const float4*)(sh2_w + col8);
  float4 wA = *(const float4*)(sh2_w + col8 + 4);
  float bvv = sh2_b[0];
  int row = w * 4 + (lane >> 4);
  uint4 raw = *(const uint4*)&Ab[row * 392 + col8];
  float acc = blo(raw.x) * w0.x + bhi(raw.x) * w0.y + blo(raw.y) * w0.z + bhi(raw.y) * w0.w +
              blo(raw.z) * wA.x + bhi(raw.z) * wA.y + blo(raw.w) * wA.z + bhi(raw.w) * wA.w;
  acc += __shfl_xor(acc, 1); acc += __shfl_xor(acc, 2);
  acc += __shfl_xor(acc, 4); acc += __shfl_xor(acc, 8);
  if ((lane & 15) == 0) out[49152 + n0 + row] = 1.f / (1.f + expf(-(acc + bvv)));
  uint4 rf = *(const uint4*)&Bb[row * 392 + col8];
  float v[8] = {blo(rf.x), bhi(rf.x), blo(rf.y), bhi(rf.y),
                blo(rf.z), bhi(rf.z), blo(rf.w), bhi(rf.w)};
  float s = 0.f;
#pragma unroll
  for (int i = 0; i < 8; ++i) s = fmaf(v[i], v[i], s);
  s += __shfl_xor(s, 1); s += __shfl_xor(s, 2);
  s += __shfl_xor(s, 4); s += __shfl_xor(s, 8);
  float inv = 1.f / fmaxf(sqrtf(s), 1e-12f);
  float* op = out + 65536 + (size_t)(n0 + row) * 128 + col8;
  *(float4*)op = make_float4(v[0] * inv, v[1] * inv, v[2] * inv, v[3] * inv);
  *(float4*)(op + 4) = make_float4(v[4] * inv, v[5] * inv, v[6] * inv, v[7] * inv);
  for (int i = t; i < 96; i += 512) out[n0 * 3 + i] = pxyz[n0 * 3 + i];
}

extern "C" void kernel_launch(void* const* d_in, const int* in_sizes, int n_in,
                              void* d_out, int out_size, void* d_ws, size_t ws_size,
                              hipStream_t stream) {
  const float* pcd_xyz = (const float*)d_in[0];
  const float* rgb_xyz = (const float*)d_in[1];
  const float* pcd_f   = (const float*)d_in[2];
  const float* rgb_f   = (const float*)d_in[3];
  const float* cc1_w = (const float*)d_in[4];  const float* cc1_b = (const float*)d_in[5];
  const float* cc_bn = (const float*)d_in[6];
  const float* cc2_w = (const float*)d_in[7];  const float* cc2_b = (const float*)d_in[8];
  const float* co1_w = (const float*)d_in[9];  const float* co1_b = (const float*)d_in[10];
  const float* co_bn = (const float*)d_in[11];
  const float* co2_w = (const float*)d_in[12]; const float* co2_b = (const float*)d_in[13];
  const float* dh1_w = (const float*)d_in[14]; const float* dh1_b = (const float*)d_in[15];
  const float* dh1_bn = (const float*)d_in[16];
  const float* dh2_w = (const float*)d_in[17]; const float* dh2_b = (const float*)d_in[18];
  const float* dh2_bn = (const float*)d_in[19];
  const float* dh3_w = (const float*)d_in[20]; const float* dh3_b = (const float*)d_in[21];
  const float* sh1_w = (const float*)d_in[22]; const float* sh1_b = (const float*)d_in[23];
  const float* sh_bn = (const float*)d_in[24];
  const float* sh2_w = (const float*)d_in[25]; const float* sh2_b = (const float*)d_in[26];

  char* ws = (char*)d_ws;
  float* out = (float*)d_out;

  unsigned short* wb    = (unsigned short*)(ws);              // 766 KB
  unsigned short* rgbTb = (unsigned short*)(ws + 0x100000);   // 2.1 MB
  float4* rxyz4         = (float4*)(ws + 0x320000);           // 128 KB
  int*    cellCnt       = (int*)(ws + 0x480000);              // 8.8 KB
  float4* cellTab       = (float4*)(ws + 0x490000);           // 984 KB
  unsigned short* fullp = (unsigned short*)(ws + 0xA00000);   // (NP,32) bf16 = 1 MB

  unsigned short* wb_cc1 = wb;
  unsigned short* wb_cc2 = wb + 147456;
  unsigned short* wb_co1 = wb + 196608;
  unsigned short* wb_co2 = wb + 262144;
  unsigned short* wb_dh1 = wb + 294912;
  unsigned short* wb_dh2 = wb + 320512;
  unsigned short* wb_dh3 = wb + 346112;
  unsigned short* wb_sh1 = wb + 366592;

  k_pre<<<969, 256, 0, stream>>>(rgb_f, rgb_xyz, pcd_f,
                                 cc1_w, cc2_w, co1_w, co2_w, dh1_w, dh2_w, dh3_w, sh1_w,
                                 rgbTb, rxyz4, fullp, wb, cellCnt);
  k_build<<<128, 64, 0, stream>>>(rxyz4, cellCnt, cellTab);
  k_mlp<<<512, 512, 0, stream>>>(rgbTb, pcd_xyz, cellCnt, cellTab, fullp,
                                 wb_cc1, wb_cc2, wb_co1, wb_co2,
                                 wb_dh1, wb_dh2, wb_dh3, wb_sh1,
                                 cc1_b, cc_bn, cc2_b, co1_b, co_bn, co2_b,
                                 dh1_b, dh1_bn, dh2_b, dh2_bn, dh3_b,
                                 sh1_b, sh_bn, sh2_w, sh2_b,
                                 out);
}